// Round 1
// baseline (1996.384 us; speedup 1.0000x reference)
//
#include <hip/hip_runtime.h>
#include <hip/hip_bf16.h>

#define DD 2048
#define SCALE 0.04419417382415922f   // 1/sqrt(512)

// ---------------- reduction helpers (256-thread blocks = 4 waves) ----------------

__device__ __forceinline__ float waveReduceSum(float v) {
  #pragma unroll
  for (int off = 32; off; off >>= 1) v += __shfl_down(v, off);
  return v;
}

__device__ __forceinline__ float blockReduceSum(float v, float* sred) {
  v = waveReduceSum(v);
  int wid = threadIdx.x >> 6, lane = threadIdx.x & 63;
  if (lane == 0) sred[wid] = v;
  __syncthreads();
  float r = (sred[0] + sred[1]) + (sred[2] + sred[3]);
  __syncthreads();
  return r;
}

__device__ __forceinline__ float geluf(float x) {
  return 0.5f * x * (1.0f + erff(x * 0.7071067811865476f));
}

// ---------------- utility ----------------

__global__ void k_zero(float* p, int n) {
  int i = blockIdx.x * 256 + threadIdx.x;
  if (i < n) p[i] = 0.0f;
}

// ---------------- generic single-vector GEMV stage (the scan workhorse) ----------
// y[row] (=|+=) act( W[row,:] . maybeLN(v0 + v1 + v2) + bias[row] )
// grid 512 x 256 threads, 4 rows per WG (1 row per wave)

template<int NADD, bool LN, bool GELU, bool RES>
__launch_bounds__(256)
__global__ void gemv1(const float* __restrict__ W, const float* __restrict__ bias,
                      const float* __restrict__ v0, const float* __restrict__ v1,
                      const float* __restrict__ v2,
                      const float* __restrict__ g, const float* __restrict__ bln,
                      float* __restrict__ y, float* __restrict__ xside)
{
  __shared__ __align__(16) float sx[DD];
  __shared__ float sred[4];
  int tid = threadIdx.x;
  float xv[8];
  #pragma unroll
  for (int i = 0; i < 8; ++i) {
    int idx = tid + i * 256;
    float v = v0[idx];
    if (NADD >= 1) v += v1[idx];
    if (NADD >= 2) v += v2[idx];
    xv[i] = v;
  }
  if (xside != nullptr && blockIdx.x == 0) {
    #pragma unroll
    for (int i = 0; i < 8; ++i) xside[tid + i * 256] = xv[i];
  }
  if (LN) {
    float s = 0.0f;
    #pragma unroll
    for (int i = 0; i < 8; ++i) s += xv[i];
    float mean = blockReduceSum(s, sred) * (1.0f / DD);
    float vs = 0.0f;
    #pragma unroll
    for (int i = 0; i < 8; ++i) { float d = xv[i] - mean; vs += d * d; }
    float var = blockReduceSum(vs, sred) * (1.0f / DD);
    float rs = 1.0f / sqrtf(var + 1e-5f);
    #pragma unroll
    for (int i = 0; i < 8; ++i) {
      int idx = tid + i * 256;
      sx[idx] = (xv[i] - mean) * rs * g[idx] + bln[idx];
    }
  } else {
    #pragma unroll
    for (int i = 0; i < 8; ++i) sx[tid + i * 256] = xv[i];
  }
  __syncthreads();

  int wid = tid >> 6, lane = tid & 63;
  int row = blockIdx.x * 4 + wid;
  const float4* Wr = (const float4*)(W + (size_t)row * DD);
  const float4* sx4 = (const float4*)sx;
  float acc = 0.0f;
  #pragma unroll
  for (int i = 0; i < 8; ++i) {
    float4 w4 = Wr[lane + i * 64];
    float4 x4 = sx4[lane + i * 64];
    acc += w4.x * x4.x + w4.y * x4.y + w4.z * x4.z + w4.w * x4.w;
  }
  acc = waveReduceSum(acc);
  if (lane == 0) {
    float val = acc + bias[row];
    if (GELU) val = geluf(val);
    if (RES) y[row] += val; else y[row] = val;
  }
}

// ---------------- phase 1: fold q into K-weights ----------------
// u[h][d] = SCALE * sum_j wk[h*512+j][d] * qv[h*512+j]   (wk = attn_in_w rows 2048..4095)
// grid = 8 d-chunks * 16 j-segments = 128

__global__ void k_ufold(const float* __restrict__ Wfull, const float* __restrict__ qv,
                        float* __restrict__ u)
{
  int seg = blockIdx.x & 15, chunk = blockIdx.x >> 4;
  int h = seg >> 2;                 // 128-row segments never cross a 512-row head
  int tid = threadIdx.x;
  __shared__ float sq[128];
  if (tid < 128) sq[tid] = qv[seg * 128 + tid];
  __syncthreads();
  int d = chunk * 256 + tid;
  const float* Wp = Wfull + (size_t)(2048 + seg * 128) * DD + d;
  float acc = 0.0f;
  #pragma unroll 4
  for (int j = 0; j < 128; ++j) acc += Wp[(size_t)j * DD] * sq[j];
  atomicAdd(&u[(h << 11) + d], acc * SCALE);
}

__global__ void k_cfold(const float* __restrict__ qv, const float* __restrict__ inb,
                        float* __restrict__ c)
{
  __shared__ float sred[4];
  int tid = threadIdx.x;
  for (int h = 0; h < 4; ++h) {
    float s = 0.0f;
    for (int j = tid; j < 512; j += 256) s += qv[h * 512 + j] * inb[2048 + h * 512 + j];
    float tot = blockReduceSum(s, sred);
    if (tid == 0) c[h] = tot * SCALE;
    __syncthreads();
  }
}

// ---------------- phase 1: scores = x . u_h + c_h ----------------
// grid = B*T = 16384

__global__ void k_scores(const float* __restrict__ x, const float* __restrict__ u,
                         const float* __restrict__ c, float* __restrict__ sc)
{
  int blk = blockIdx.x;
  int b = blk >> 10, t = blk & 1023;
  int tid = threadIdx.x, wid = tid >> 6, lane = tid & 63;
  const float4* xr = (const float4*)(x + (size_t)blk * DD);
  float acc[4] = {0, 0, 0, 0};
  #pragma unroll
  for (int i = 0; i < 2; ++i) {
    int f = tid + i * 256;
    float4 x4 = xr[f];
    #pragma unroll
    for (int h = 0; h < 4; ++h) {
      float4 u4 = ((const float4*)(u + (h << 11)))[f];
      acc[h] += x4.x * u4.x + x4.y * u4.y + x4.z * u4.z + x4.w * u4.w;
    }
  }
  __shared__ float sred[4][4];
  #pragma unroll
  for (int h = 0; h < 4; ++h) {
    float v = waveReduceSum(acc[h]);
    if (lane == 0) sred[h][wid] = v;
  }
  __syncthreads();
  if (tid < 4) {
    float v = sred[tid][0] + sred[tid][1] + sred[tid][2] + sred[tid][3] + c[tid];
    sc[((size_t)(b * 4 + tid) << 10) + t] = v;
  }
}

// ---------------- softmax over T per (b,h) row; in place. grid = 64 ------------

__global__ void k_softmax(float* __restrict__ s)
{
  __shared__ float sred[4];
  int tid = threadIdx.x, wid = tid >> 6, lane = tid & 63;
  float* p = s + ((size_t)blockIdx.x << 10);
  float v[4];
  #pragma unroll
  for (int i = 0; i < 4; ++i) v[i] = p[tid + i * 256];
  float m = fmaxf(fmaxf(v[0], v[1]), fmaxf(v[2], v[3]));
  #pragma unroll
  for (int off = 32; off; off >>= 1) m = fmaxf(m, __shfl_down(m, off));
  if (lane == 0) sred[wid] = m;
  __syncthreads();
  m = fmaxf(fmaxf(sred[0], sred[1]), fmaxf(sred[2], sred[3]));
  __syncthreads();
  float e[4], sum = 0.0f;
  #pragma unroll
  for (int i = 0; i < 4; ++i) { e[i] = expf(v[i] - m); sum += e[i]; }
  float tot = blockReduceSum(sum, sred);
  float inv = 1.0f / tot;
  #pragma unroll
  for (int i = 0; i < 4; ++i) p[tid + i * 256] = e[i] * inv;
}

// ---------------- xbar[b,h,:] = sum_t att[b,h,t] * x[b,t,:] (2-pass) -----------
// pass 1: partials over 8 t-segments. grid = 16b * 8chunk * 8seg = 1024

__global__ void k_xbar_part(const float* __restrict__ x, const float* __restrict__ att,
                            float* __restrict__ part)
{
  int blk = blockIdx.x;
  int seg = blk & 7, chunk = (blk >> 3) & 7, b = blk >> 6;
  int tid = threadIdx.x;
  __shared__ float satt[4][128];
  for (int i = tid; i < 512; i += 256) {
    int h = i >> 7, j = i & 127;
    satt[h][j] = att[((size_t)(b * 4 + h) << 10) + seg * 128 + j];
  }
  __syncthreads();
  int d = chunk * 256 + tid;
  const float* xb = x + ((size_t)b * 1024 + seg * 128) * DD + d;
  float a0 = 0, a1 = 0, a2 = 0, a3 = 0;
  #pragma unroll 4
  for (int j = 0; j < 128; ++j) {
    float xv = xb[(size_t)j * DD];
    a0 += satt[0][j] * xv; a1 += satt[1][j] * xv;
    a2 += satt[2][j] * xv; a3 += satt[3][j] * xv;
  }
  size_t base = ((size_t)(b * 8 + seg) * 4);
  part[((base + 0) << 11) + d] = a0;
  part[((base + 1) << 11) + d] = a1;
  part[((base + 2) << 11) + d] = a2;
  part[((base + 3) << 11) + d] = a3;
}

// pass 2: reduce 8 segments. grid = 131072/256 = 512
__global__ void k_xbar_red(const float* __restrict__ part, float* __restrict__ xbar)
{
  int i = blockIdx.x * 256 + threadIdx.x;   // over 16*4*2048
  int d = i & 2047; int h = (i >> 11) & 3; int b = i >> 13;
  float s = 0.0f;
  #pragma unroll
  for (int seg = 0; seg < 8; ++seg)
    s += part[(((size_t)(b * 8 + seg) * 4 + h) << 11) + d];
  xbar[i] = s;
}

// ---------------- o[b, h*512+r] = wv[h*512+r,:] . xbar[b,h,:] + bv -------------
// grid 256 (8 rows each, all same head), batch 16 staged 8 at a time (64KB LDS)

__launch_bounds__(256)
__global__ void k_vproj(const float* __restrict__ inW, const float* __restrict__ inB,
                        const float* __restrict__ xbar, float* __restrict__ o)
{
  __shared__ __align__(16) float sv[8][DD];
  int tid = threadIdx.x, wid = tid >> 6, lane = tid & 63;
  int row0 = blockIdx.x * 8;
  int h = row0 >> 9;
  int rowA = row0 + wid, rowB = row0 + 4 + wid;
  const float4* WA = (const float4*)(inW + (size_t)(4096 + rowA) * DD);
  const float4* WB = (const float4*)(inW + (size_t)(4096 + rowB) * DD);
  float4 wa[8], wb[8];
  #pragma unroll
  for (int i = 0; i < 8; ++i) { wa[i] = WA[lane + i * 64]; wb[i] = WB[lane + i * 64]; }
  float accA[16], accB[16];
  #pragma unroll
  for (int b = 0; b < 16; ++b) { accA[b] = 0; accB[b] = 0; }
  for (int half = 0; half < 2; ++half) {
    __syncthreads();
    for (int i = tid; i < 8 * 512; i += 256) {
      int b = i >> 9, f = i & 511;
      ((float4*)&sv[b][0])[f] =
          ((const float4*)(xbar + (((size_t)(half * 8 + b) * 4 + h) << 11)))[f];
    }
    __syncthreads();
    #pragma unroll
    for (int i = 0; i < 8; ++i) {
      int f = lane + i * 64;
      #pragma unroll
      for (int b = 0; b < 8; ++b) {
        float4 x4 = ((const float4*)&sv[b][0])[f];
        accA[half * 8 + b] += wa[i].x * x4.x + wa[i].y * x4.y + wa[i].z * x4.z + wa[i].w * x4.w;
        accB[half * 8 + b] += wb[i].x * x4.x + wb[i].y * x4.y + wb[i].z * x4.z + wb[i].w * x4.w;
      }
    }
  }
  #pragma unroll
  for (int b = 0; b < 16; ++b) {
    float v = waveReduceSum(accA[b]);
    if (lane == 0) o[((size_t)b << 11) + rowA] = v + inB[4096 + rowA];
    v = waveReduceSum(accB[b]);
    if (lane == 0) o[((size_t)b << 11) + rowB] = v + inB[4096 + rowB];
  }
}

// ---------------- batched (16) GEMV: y[b] = act(W @ vin[b] + bias) -------------
// grid 256, same structure as k_vproj but full-D shared input per batch

template<bool GELU>
__launch_bounds__(256)
__global__ void gemvB(const float* __restrict__ W, const float* __restrict__ bias,
                      const float* __restrict__ vin, float* __restrict__ y)
{
  __shared__ __align__(16) float sv[8][DD];
  int tid = threadIdx.x, wid = tid >> 6, lane = tid & 63;
  int row0 = blockIdx.x * 8;
  int rowA = row0 + wid, rowB = row0 + 4 + wid;
  const float4* WA = (const float4*)(W + (size_t)rowA * DD);
  const float4* WB = (const float4*)(W + (size_t)rowB * DD);
  float4 wa[8], wb[8];
  #pragma unroll
  for (int i = 0; i < 8; ++i) { wa[i] = WA[lane + i * 64]; wb[i] = WB[lane + i * 64]; }
  float accA[16], accB[16];
  #pragma unroll
  for (int b = 0; b < 16; ++b) { accA[b] = 0; accB[b] = 0; }
  for (int half = 0; half < 2; ++half) {
    __syncthreads();
    for (int i = tid; i < 8 * 512; i += 256) {
      int b = i >> 9, f = i & 511;
      ((float4*)&sv[b][0])[f] =
          ((const float4*)(vin + ((size_t)(half * 8 + b) << 11)))[f];
    }
    __syncthreads();
    #pragma unroll
    for (int i = 0; i < 8; ++i) {
      int f = lane + i * 64;
      #pragma unroll
      for (int b = 0; b < 8; ++b) {
        float4 x4 = ((const float4*)&sv[b][0])[f];
        accA[half * 8 + b] += wa[i].x * x4.x + wa[i].y * x4.y + wa[i].z * x4.z + wa[i].w * x4.w;
        accB[half * 8 + b] += wb[i].x * x4.x + wb[i].y * x4.y + wb[i].z * x4.z + wb[i].w * x4.w;
      }
    }
  }
  #pragma unroll
  for (int b = 0; b < 16; ++b) {
    float v = waveReduceSum(accA[b]);
    if (lane == 0) {
      float r = v + bias[rowA];
      if (GELU) r = geluf(r);
      y[((size_t)b << 11) + rowA] = r;
    }
    v = waveReduceSum(accB[b]);
    if (lane == 0) {
      float r = v + bias[rowB];
      if (GELU) r = geluf(r);
      y[((size_t)b << 11) + rowB] = r;
    }
  }
}

// ---------------- final LayerNorm -> d_out (2048) ----------------

__global__ void k_final_ln(const float* __restrict__ z, const float* __restrict__ g,
                           const float* __restrict__ b, float* __restrict__ out)
{
  __shared__ float sred[4];
  int tid = threadIdx.x;
  float xv[8];
  #pragma unroll
  for (int i = 0; i < 8; ++i) xv[i] = z[tid + i * 256];
  float s = 0.0f;
  #pragma unroll
  for (int i = 0; i < 8; ++i) s += xv[i];
  float mean = blockReduceSum(s, sred) * (1.0f / DD);
  float vs = 0.0f;
  #pragma unroll
  for (int i = 0; i < 8; ++i) { float d = xv[i] - mean; vs += d * d; }
  float var = blockReduceSum(vs, sred) * (1.0f / DD);
  float rs = 1.0f / sqrtf(var + 1e-5f);
  #pragma unroll
  for (int i = 0; i < 8; ++i) {
    int idx = tid + i * 256;
    out[idx] = (xv[i] - mean) * rs * g[idx] + b[idx];
  }
}

// ======================= host side =======================

struct BlockP {
  const float *in_w, *in_b, *out_w, *out_b, *n1g, *n1b, *n2g, *n2b, *f1w, *f1b, *f2w, *f2b;
};

// one CoT block on a single 2048-vector:
//   x = z + i1 (+ i2); x += out_w @ LN1(x)->wv-proj path; x += f2 @ gelu(f1 @ LN2(x))
// result lands in xb (which becomes the new z)
static void runBlock(const BlockP& p, const float* z, float* xb,
                     const float* i1, const float* i2,
                     float* tbuf, float* hbuf, hipStream_t stream)
{
  const float* wv = p.in_w + (size_t)4096 * DD;
  const float* bv = p.in_b + 4096;
  if (i2)
    gemv1<2, true, false, false><<<512, 256, 0, stream>>>(wv, bv, z, i1, i2, p.n1g, p.n1b, tbuf, xb);
  else
    gemv1<1, true, false, false><<<512, 256, 0, stream>>>(wv, bv, z, i1, nullptr, p.n1g, p.n1b, tbuf, xb);
  gemv1<0, false, false, true><<<512, 256, 0, stream>>>(p.out_w, p.out_b, tbuf, nullptr, nullptr, nullptr, nullptr, xb, nullptr);
  gemv1<0, true, true, false><<<512, 256, 0, stream>>>(p.f1w, p.f1b, xb, nullptr, nullptr, p.n2g, p.n2b, hbuf, nullptr);
  gemv1<0, false, false, true><<<512, 256, 0, stream>>>(p.f2w, p.f2b, hbuf, nullptr, nullptr, nullptr, nullptr, xb, nullptr);
}

extern "C" void kernel_launch(void* const* d_in, const int* in_sizes, int n_in,
                              void* d_out, int out_size, void* d_ws, size_t ws_size,
                              hipStream_t stream)
{
  const float* x          = (const float*)d_in[0];
  const float* gq         = (const float*)d_in[1];
  const float* attn_in_w  = (const float*)d_in[2];
  const float* attn_in_b  = (const float*)d_in[3];
  const float* attn_out_w = (const float*)d_in[4];
  const float* attn_out_b = (const float*)d_in[5];
  const float* mlp1_w     = (const float*)d_in[6];
  const float* mlp1_b     = (const float*)d_in[7];
  const float* mlp2_w     = (const float*)d_in[8];
  const float* mlp2_b     = (const float*)d_in[9];
  BlockP Hp = { (const float*)d_in[10], (const float*)d_in[11], (const float*)d_in[12],
                (const float*)d_in[13], (const float*)d_in[14], (const float*)d_in[15],
                (const float*)d_in[16], (const float*)d_in[17], (const float*)d_in[18],
                (const float*)d_in[19], (const float*)d_in[20], (const float*)d_in[21] };
  BlockP Lp = { (const float*)d_in[22], (const float*)d_in[23], (const float*)d_in[24],
                (const float*)d_in[25], (const float*)d_in[26], (const float*)d_in[27],
                (const float*)d_in[28], (const float*)d_in[29], (const float*)d_in[30],
                (const float*)d_in[31], (const float*)d_in[32], (const float*)d_in[33] };
  const float* norm_g = (const float*)d_in[34];
  const float* norm_b = (const float*)d_in[35];

  float* ws = (float*)d_ws;
  float* u     = ws + 0;        // 4*2048
  float* zL[2] = { ws + 8192,  ws + 12288 };
  float* zH[2] = { ws + 10240, ws + 14336 };
  float* qv    = ws + 16384;    // 2048
  float* c     = ws + 18432;    // 4 (pad 64)
  float* tbuf  = ws + 18496;    // 2048
  float* hbuf  = ws + 20544;    // 2048
  float* sc    = ws + 22592;    // 16*4*1024
  float* xbar  = ws + 88128;    // 16*4*2048
  float* o     = ws + 219200;   // 16*2048
  float* a0    = ws + 251968;   // 16*2048
  float* a1    = ws + 284736;   // 16*2048
  float* abuf  = ws + 317504;   // 16*2048
  float* part  = ws + 350272;   // 16*8*4*2048 = 1M floats

  // zero: u + zL0 + zH0 (contiguous first 12288 floats)
  k_zero<<<48, 256, 0, stream>>>(ws, 12288);

  // --- phase 1: a = MLP(out_proj(attn(q_global, x, x))) ---
  // qv = wq @ gq + bq
  gemv1<0, false, false, false><<<512, 256, 0, stream>>>(
      attn_in_w, attn_in_b, gq, nullptr, nullptr, nullptr, nullptr, qv, nullptr);
  k_ufold<<<128, 256, 0, stream>>>(attn_in_w, qv, u);
  k_cfold<<<1, 256, 0, stream>>>(qv, attn_in_b, c);
  k_scores<<<16384, 256, 0, stream>>>(x, u, c, sc);
  k_softmax<<<64, 256, 0, stream>>>(sc);
  k_xbar_part<<<1024, 256, 0, stream>>>(x, sc, part);
  k_xbar_red<<<512, 256, 0, stream>>>(part, xbar);
  k_vproj<<<256, 256, 0, stream>>>(attn_in_w, attn_in_b, xbar, o);
  gemvB<false><<<256, 256, 0, stream>>>(attn_out_w, attn_out_b, o, a0);
  gemvB<true ><<<256, 256, 0, stream>>>(mlp1_w, mlp1_b, a0, a1);
  gemvB<false><<<256, 256, 0, stream>>>(mlp2_w, mlp2_b, a1, abuf);

  // --- phase 2: sequential scan, 16 steps x (3 L-blocks + 1 H-block) ---
  int li = 0, hi = 0;
  for (int s = 0; s < 16; ++s) {
    const float* xt = abuf + (size_t)s * DD;
    for (int r = 0; r < 3; ++r) {
      runBlock(Lp, zL[li], zL[li ^ 1], zH[hi], xt, tbuf, hbuf, stream);
      li ^= 1;
    }
    runBlock(Hp, zH[hi], zH[hi ^ 1], zL[li], nullptr, tbuf, hbuf, stream);
    hi ^= 1;
  }

  // --- final LN on zH -> d_out (2048 f32) ---
  k_final_ln<<<1, 256, 0, stream>>>(zH[hi], norm_g, norm_b, (float*)d_out);
}